// Round 18
// baseline (425.842 us; speedup 1.0000x reference)
//
#include <hip/hip_runtime.h>
#include <math.h>

#define NNODES 20000
#define NEDGES 320000
#define NB 79      // ceil(NNODES/256)

typedef __bf16 bf16x8 __attribute__((ext_vector_type(8)));
typedef float f32x4 __attribute__((ext_vector_type(4)));
typedef unsigned short u16x8 __attribute__((ext_vector_type(8)));

__device__ inline unsigned short f2bf(float x) {
  union { float f; unsigned int u; } q;
  q.f = x;
  unsigned int u = q.u;
  unsigned int r = (u + 0x7fffu + ((u >> 16) & 1u)) >> 16;
  return (unsigned short)r;
}

__device__ inline float bf2f(unsigned short u) {
  union { unsigned int u; float f; } q;
  q.u = ((unsigned int)u) << 16;
  return q.f;
}

// async 16B global->LDS (wave-uniform LDS base + lane*16; per-lane global src)
__device__ inline void load_lds16(const unsigned short* g, unsigned short* l) {
  __builtin_amdgcn_global_load_lds(
      (const __attribute__((address_space(1))) unsigned int*)g,
      (__attribute__((address_space(3))) unsigned int*)l, 16, 0, 0);
}

// ---------------- init: zero cnt + stats ----------------
__global__ __launch_bounds__(256) void init_kernel(int* __restrict__ cnt,
                                                   float* __restrict__ stats) {
  int idx = blockIdx.x * 256 + threadIdx.x;
  if (idx < NNODES) cnt[idx] = 0;
  int j = idx - NNODES;
  if (j >= 0 && j < 4096) stats[j] = 0.f;
}

// ---------------- fused: count (blocks 0..1249) + embed (rest) ----------------
__global__ __launch_bounds__(256) void count_embed_kernel(
    const int* __restrict__ edst, int* __restrict__ cnt,
    const float* __restrict__ x, unsigned short* __restrict__ h) {
  int bid = blockIdx.x;
  if (bid < 1250) {
    int e = bid * 256 + threadIdx.x;
    atomicAdd(&cnt[edst[e]], 1);
    return;
  }
  int n = (bid - 1250) * 256 + threadIdx.x;
  if (n >= NNODES) return;
  const float* xr = x + (size_t)n * 20;
  unsigned short* hr = h + (size_t)n * 256;
#pragma unroll
  for (int g = 0; g < 3; ++g) {
    float v0 = xr[g * 3 + 0], v1 = xr[g * 3 + 1], v2 = xr[g * 3 + 2];
    unsigned short* o = hr + g * 63;
    o[0] = f2bf(v0); o[1] = f2bf(v1); o[2] = f2bf(v2);
    float f = 1.0f;
    for (int fr = 0; fr < 10; ++fr) {
      float s0, c0, s1, c1, s2, c2;
      sincosf(v0 * f, &s0, &c0);
      sincosf(v1 * f, &s1, &c1);
      sincosf(v2 * f, &s2, &c2);
      int base = 3 + fr * 6;
      o[base + 0] = f2bf(s0); o[base + 1] = f2bf(s1); o[base + 2] = f2bf(s2);
      o[base + 3] = f2bf(c0); o[base + 4] = f2bf(c1); o[base + 5] = f2bf(c2);
      f *= 2.0f;
    }
  }
  for (int j = 0; j < 11; ++j) hr[189 + j] = f2bf(xr[9 + j]);
  for (int j = 200; j < 256; ++j) hr[j] = 0;
}

// ---------------- scan pass1: per-block sums ----------------
__global__ __launch_bounds__(256) void scan_pass1(const int* __restrict__ cnt,
                                                  int* __restrict__ bsum) {
  __shared__ int red[256];
  int i = blockIdx.x * 256 + threadIdx.x;
  int v = (i < NNODES) ? cnt[i] : 0;
  red[threadIdx.x] = v;
  __syncthreads();
#pragma unroll
  for (int off = 128; off > 0; off >>= 1) {
    if (threadIdx.x < off) red[threadIdx.x] += red[threadIdx.x + off];
    __syncthreads();
  }
  if (threadIdx.x == 0) bsum[blockIdx.x] = red[0];
}

// ---------------- scan pass3: redundant bsum-scan + local scan -> rowptr/head ----
__global__ __launch_bounds__(256) void scan_pass3(const int* __restrict__ cnt,
                                                  const int* __restrict__ bsum,
                                                  int* __restrict__ rowptr,
                                                  int* __restrict__ head) {
  __shared__ int pref[128];
  __shared__ int buf[256];
  int t = threadIdx.x;
  if (t < 128) {
    int v = (t < NB) ? bsum[t] : 0;
    pref[t] = v;
  }
  __syncthreads();
#pragma unroll
  for (int off = 1; off < 128; off <<= 1) {
    int u = (t < 128 && t >= off) ? pref[t - off] : 0;
    __syncthreads();
    if (t < 128) pref[t] += u;
    __syncthreads();
  }
  int boff = (blockIdx.x == 0) ? 0 : pref[blockIdx.x - 1];
  int i = blockIdx.x * 256 + t;
  int v = (i < NNODES) ? cnt[i] : 0;
  buf[t] = v;
  __syncthreads();
#pragma unroll
  for (int off = 1; off < 256; off <<= 1) {
    int u = (t >= off) ? buf[t - off] : 0;
    __syncthreads();
    buf[t] += u;
    __syncthreads();
  }
  if (i < NNODES) {
    int excl = boff + buf[t] - v;
    rowptr[i] = excl;
    head[i] = excl;
  }
  if (i == 0) rowptr[NNODES] = NEDGES;
}

// ---------------- fused: scatter (blocks 0..1249) + weight prep (rest) ----------
struct WPtrs {
  const float* w1[5];
  const float* w2[5];
};

#define WT1_TOTAL 507904
#define WT2_TOTAL 413696

__global__ __launch_bounds__(256) void scatter_prep_kernel(
    const int* __restrict__ esrc, const int* __restrict__ edst,
    int* __restrict__ head, int* __restrict__ csr_src, WPtrs p,
    unsigned short* __restrict__ Wt1All, unsigned short* __restrict__ Wt2All) {
  int bid = blockIdx.x;
  if (bid < 1250) {
    int e = bid * 256 + threadIdx.x;
    int pos = atomicAdd(&head[edst[e]], 1);
    csr_src[pos] = esrc[e];
    return;
  }
  int idx = (bid - 1250) * 256 + threadIdx.x;
  if (idx < WT1_TOTAL) {
    int L, off, din, dout, Kpad;
    if (idx < 32768)       { L = 0; off = 0;      din = 200; dout = 64;  Kpad = 256; }
    else if (idx < 49152)  { L = 1; off = 32768;  din = 64;  dout = 128; Kpad = 64;  }
    else if (idx < 114688) { L = 2; off = 49152;  din = 128; dout = 256; Kpad = 128; }
    else if (idx < 245760) { L = 3; off = 114688; din = 256; dout = 256; Kpad = 256; }
    else                   { L = 4; off = 245760; din = 256; dout = 512; Kpad = 256; }
    int local = idx - off;
    int c = local / Kpad, k = local % Kpad;
    float v = 0.f;
    if (k < din)
      v = (c < dout) ? p.w1[L][(size_t)k * dout + c]
                     : p.w1[L][(size_t)(din + k) * dout + (c - dout)];
    Wt1All[idx] = f2bf(v);
    return;
  }
  int jdx = idx - WT1_TOTAL;
  if (jdx >= WT2_TOTAL) return;
  int L, off, d;
  if (jdx < 4096)        { L = 0; off = 0;      d = 64;  }
  else if (jdx < 20480)  { L = 1; off = 4096;   d = 128; }
  else if (jdx < 86016)  { L = 2; off = 20480;  d = 256; }
  else if (jdx < 151552) { L = 3; off = 86016;  d = 256; }
  else                   { L = 4; off = 151552; d = 512; }
  int local = jdx - off;
  int n = local / d, k = local % d;
  Wt2All[jdx] = f2bf(p.w2[L][(size_t)k * d + n]);
}

// ======== BMxBN MFMA GEMM, BK=64, XCD-aware 1D grid, high-occupancy ========
// BM in {32,64}, BN in {64,128}. LDS: sA[BM][64] + sB[BN][64], chunk-XOR swizzle.
// C-write via LDS transpose -> 16B-coalesced stores. s_setprio(1) around MFMA.
// EPIA 0: A bf16 via gload_lds; EPIA 1: A bf16 S with fused BN+ReLU.
// EPI 0: Cout bf16 = acc + (col<dhalf ? bias : 0)
// EPI 1: Cout f32  = cnt[row]>0 ? acc + bias : 0        (final layer; BN=128)
// EPI 2: Cout bf16 = masked+bias, + atomic column stats (sum, sumsq)
template <int EPI, int EPIA, int BM, int BN>
__global__ __launch_bounds__(256) void gemm128_kernel(
    const void* __restrict__ Aptr, int lda, int K, int ncolb,
    const unsigned short* __restrict__ Bt, int Ncol, int dhalf,
    const float* __restrict__ bias, const int* __restrict__ cnt,
    const float* __restrict__ pstats, const float* __restrict__ pg,
    const float* __restrict__ pb, float* __restrict__ stats,
    void* __restrict__ Cout) {
  constexpr int NFR = BM / 16;          // row fragments (32->2, 64->4)
  constexpr int NFC = BN / 64;          // col fragments per wave
  constexpr int AGRP = BM / 32;         // A stage loads per wave
  constexpr int BGRP = BN / 32;         // B stage loads per wave
  constexpr int MBM = (NNODES + BM - 1) / BM;
  constexpr int MQ_ = MBM / 8;
  constexpr int MR_ = MBM % 8;
  int bid = blockIdx.x;
  int xcd = bid & 7;
  int j = bid >> 3;
  int cntx = MQ_ + (xcd < MR_ ? 1 : 0);
  int row_local = j / ncolb;
  if (row_local >= cntx) return;
  int colb = j - row_local * ncolb;
  int row0 = xcd * MQ_ + min(xcd, MR_);
  int bR = (row0 + row_local) * BM;
  int bC = colb * BN;

  __shared__ unsigned short sBuf[BM * 64 + BN * 64];
  __shared__ float sScale[EPIA == 1 ? 256 : 1], sShift[EPIA == 1 ? 256 : 1];
  unsigned short* sA = sBuf;             // [BM][64]
  unsigned short* sB = sBuf + BM * 64;   // [BN][64]
  int tid = threadIdx.x;
  int wid = tid >> 6, lane = tid & 63;
  int lr = lane & 15, lg = lane >> 4;
  int sub = lane >> 3;
  int ckl = (lane & 7) ^ sub;  // inverse-swizzled source chunk for gload_lds

  if (EPIA == 1) {
    for (int c = tid; c < K; c += 256) {
      float mu = pstats[c] * (1.0f / NNODES);
      float var = pstats[K + c] * (1.0f / NNODES) - mu * mu;
      float sc = pg[c] * rsqrtf(var + 1e-5f);
      sScale[c] = sc;
      sShift[c] = pb[c] - mu * sc;
    }
    __syncthreads();
  }

  f32x4 acc[NFR][NFC];
#pragma unroll
  for (int fr = 0; fr < NFR; ++fr)
#pragma unroll
    for (int fc = 0; fc < NFC; ++fc) acc[fr][fc] = f32x4{0.f, 0.f, 0.f, 0.f};

  for (int k0 = 0; k0 < K; k0 += 64) {
    // ---- stage A tile [BM][64] ----
    if (EPIA == 0) {
      const unsigned short* Ab = (const unsigned short*)Aptr;
#pragma unroll
      for (int q = 0; q < AGRP; ++q) {
        int t = wid * AGRP + q;
        int gr = bR + t * 8 + sub;
        if (gr > NNODES - 1) gr = NNODES - 1;  // clamp; rows >= N never written out
        load_lds16(Ab + (size_t)gr * lda + k0 + ckl * 8, sA + t * 512);
      }
    } else {
      const unsigned short* Ab = (const unsigned short*)Aptr;
#pragma unroll
      for (int i = 0; i < BM / 32; ++i) {
        int idx = tid + i * 256;
        int row = idx >> 3, c = idx & 7;
        int gr = bR + row;
        u16x8 o;
        if (gr < NNODES) {
          u16x8 s8 = *(const u16x8*)(Ab + (size_t)gr * lda + k0 + c * 8);
#pragma unroll
          for (int jj = 0; jj < 8; ++jj) {
            int k = k0 + c * 8 + jj;
            o[jj] = f2bf(fmaxf(bf2f(s8[jj]) * sScale[k] + sShift[k], 0.f));
          }
        } else {
#pragma unroll
          for (int jj = 0; jj < 8; ++jj) o[jj] = 0;
        }
        int ck = c ^ (row & 7);
        *(u16x8*)(sA + row * 64 + ck * 8) = o;
      }
    }
    // ---- stage B tile [BN][64] ----
#pragma unroll
    for (int q = 0; q < BGRP; ++q) {
      int t = wid * BGRP + q;
      int gn = bC + t * 8 + sub;
      load_lds16(Bt + (size_t)gn * K + k0 + ckl * 8, sB + t * 512);
    }
    __syncthreads();
    __builtin_amdgcn_s_setprio(1);
#pragma unroll
    for (int ks = 0; ks < 2; ++ks) {
      bf16x8 aF[NFR], bF[NFC];
      int cb = ks * 4 + lg;
      int ck = cb ^ (lr & 7);
#pragma unroll
      for (int fr = 0; fr < NFR; ++fr)
        aF[fr] = *(const bf16x8*)(sA + (fr * 16 + lr) * 64 + ck * 8);
#pragma unroll
      for (int fc = 0; fc < NFC; ++fc)
        bF[fc] = *(const bf16x8*)(sB + (wid * NFC * 16 + fc * 16 + lr) * 64 + ck * 8);
#pragma unroll
      for (int fr = 0; fr < NFR; ++fr)
#pragma unroll
        for (int fc = 0; fc < NFC; ++fc)
          acc[fr][fc] = __builtin_amdgcn_mfma_f32_16x16x32_bf16(
              aF[fr], bF[fc], acc[fr][fc], 0, 0, 0);
    }
    __builtin_amdgcn_s_setprio(0);
    __syncthreads();
  }

  // ---- epilogue ----
  if constexpr (EPI == 0 || EPI == 2) {
    float csum[NFC], csum2[NFC];
#pragma unroll
    for (int fc = 0; fc < NFC; ++fc) { csum[fc] = 0.f; csum2[fc] = 0.f; }
#pragma unroll
    for (int fr = 0; fr < NFR; ++fr) {
#pragma unroll
      for (int jj = 0; jj < 4; ++jj) {
        int row = fr * 16 + lg * 4 + jj;
        int gr = bR + row;
        int ct = 1;
        if (EPI == 2) ct = (gr < NNODES) ? cnt[gr] : 0;
#pragma unroll
        for (int fc = 0; fc < NFC; ++fc) {
          int col = wid * NFC * 16 + fc * 16 + lr;
          int gc = bC + col;
          float v = acc[fr][fc][jj];
          if (EPI == 0) {
            if (gc < dhalf) v += bias[gc];
          } else {
            v = (ct > 0) ? (v + bias[gc]) : 0.f;
            if (gr < NNODES) {
              csum[fc] += v;
              csum2[fc] += v * v;
            }
          }
          sBuf[row * BN + col] = f2bf(v);
        }
      }
    }
    if (EPI == 2) {
#pragma unroll
      for (int fc = 0; fc < NFC; ++fc) {
        float s = csum[fc], s2 = csum2[fc];
        s += __shfl_xor(s, 16, 64);
        s += __shfl_xor(s, 32, 64);
        s2 += __shfl_xor(s2, 16, 64);
        s2 += __shfl_xor(s2, 32, 64);
        if (lg == 0) {
          int gc = bC + wid * NFC * 16 + fc * 16 + lr;
          atomicAdd(&stats[gc], s);
          atomicAdd(&stats[Ncol + gc], s2);
        }
      }
    }
    __syncthreads();
#pragma unroll
    for (int i = 0; i < BM * BN / 2048; ++i) {
      int idx = tid + i * 256;
      int row = idx / (BN / 8), c8 = (idx % (BN / 8)) * 8;
      int gr = bR + row;
      if (gr < NNODES)
        *(u16x8*)((unsigned short*)Cout + (size_t)gr * Ncol + bC + c8) =
            *(const u16x8*)(sBuf + row * BN + c8);
    }
  } else {
    // EPI 1 (BN=128 only): f32 output in two col-half passes via BMx64 f32 tile
    float* sF = (float*)sBuf;
#pragma unroll
    for (int h = 0; h < 2; ++h) {
      if ((wid >> 1) == h) {
#pragma unroll
        for (int fr = 0; fr < NFR; ++fr) {
#pragma unroll
          for (int jj = 0; jj < 4; ++jj) {
            int row = fr * 16 + lg * 4 + jj;
            int gr = bR + row;
            int ct = (gr < NNODES) ? cnt[gr] : 0;
#pragma unroll
            for (int fc = 0; fc < NFC; ++fc) {
              int lcol = (wid & 1) * 32 + fc * 16 + lr;
              int gc = bC + h * 64 + lcol;
              float v = acc[fr][fc][jj];
              v = (ct > 0) ? (v + bias[gc]) : 0.f;
              sF[row * 64 + lcol] = v;
            }
          }
        }
      }
      __syncthreads();
#pragma unroll
      for (int i = 0; i < BM / 16; ++i) {
        int idx = tid + i * 256;
        int row = idx >> 4, c4 = (idx & 15) * 4;
        int gr = bR + row;
        if (gr < NNODES)
          *(float4*)((float*)Cout + (size_t)gr * Ncol + bC + h * 64 + c4) =
              *(const float4*)(sF + row * 64 + c4);
      }
      __syncthreads();
    }
  }
}

// grid size helper: 8 * (MBM/8 + 1) * ncolb for BM
#define GRID32(ncolb) (8 * (625 / 8 + 1) * (ncolb))

// ------- edge aggregation (gather, bf16, XCD column-sliced, 4-deep unroll) -------
template <int D, int SLICES>
__global__ __launch_bounds__(256) void edge_agg_kernel(
    const unsigned short* __restrict__ AV, const int* __restrict__ rowptr,
    const int* __restrict__ csr_src, unsigned short* __restrict__ Y) {
  int slice = blockIdx.x % SLICES;
  int ngrp = blockIdx.x / SLICES;
  int tid = threadIdx.x;
  int ln = tid & 7;
  int sn = tid >> 3;
  int node = ngrp * 32 + sn;
  if (node >= NNODES) return;
  int c = slice * 64 + ln * 8;
  const unsigned short* Arow = AV + (size_t)node * 2 * D;
  u16x8 a8 = *(const u16x8*)(Arow + c);
  u16x8 v8 = *(const u16x8*)(Arow + D + c);
  float ad[8], acc[8];
#pragma unroll
  for (int i = 0; i < 8; ++i) {
    ad[i] = bf2f(a8[i]) - bf2f(v8[i]);
    acc[i] = 0.f;
  }
  int e0 = rowptr[node], e1 = rowptr[node + 1];
  int e = e0;
  for (; e + 3 < e1; e += 4) {
    int s0 = csr_src[e], s1 = csr_src[e + 1];
    int s2 = csr_src[e + 2], s3 = csr_src[e + 3];
    u16x8 w0 = *(const u16x8*)(AV + (size_t)s0 * 2 * D + D + c);
    u16x8 w1 = *(const u16x8*)(AV + (size_t)s1 * 2 * D + D + c);
    u16x8 w2 = *(const u16x8*)(AV + (size_t)s2 * 2 * D + D + c);
    u16x8 w3 = *(const u16x8*)(AV + (size_t)s3 * 2 * D + D + c);
#pragma unroll
    for (int i = 0; i < 8; ++i) {
      acc[i] += fmaxf(ad[i] + bf2f(w0[i]), 0.f) + fmaxf(ad[i] + bf2f(w1[i]), 0.f) +
                fmaxf(ad[i] + bf2f(w2[i]), 0.f) + fmaxf(ad[i] + bf2f(w3[i]), 0.f);
    }
  }
  for (; e < e1; ++e) {
    int s0 = csr_src[e];
    u16x8 w0 = *(const u16x8*)(AV + (size_t)s0 * 2 * D + D + c);
#pragma unroll
    for (int i = 0; i < 8; ++i) acc[i] += fmaxf(ad[i] + bf2f(w0[i]), 0.f);
  }
  float inv = (e1 > e0) ? 1.f / (float)(e1 - e0) : 0.f;
  u16x8 o;
#pragma unroll
  for (int i = 0; i < 8; ++i) o[i] = f2bf(acc[i] * inv);
  *(u16x8*)(Y + (size_t)node * D + c) = o;
}

static void launch_edge_agg(int dout, const unsigned short* AV, const int* rowptr,
                            const int* csr_src, unsigned short* Y,
                            hipStream_t st) {
  const int NG = (NNODES + 31) / 32;
  switch (dout) {
    case 64:
      hipLaunchKernelGGL((edge_agg_kernel<64, 1>), dim3(NG * 1), dim3(256), 0, st,
                         AV, rowptr, csr_src, Y);
      break;
    case 128:
      hipLaunchKernelGGL((edge_agg_kernel<128, 2>), dim3(NG * 2), dim3(256), 0, st,
                         AV, rowptr, csr_src, Y);
      break;
    case 256:
      hipLaunchKernelGGL((edge_agg_kernel<256, 4>), dim3(NG * 4), dim3(256), 0, st,
                         AV, rowptr, csr_src, Y);
      break;
    case 512:
      hipLaunchKernelGGL((edge_agg_kernel<512, 8>), dim3(NG * 8), dim3(256), 0, st,
                         AV, rowptr, csr_src, Y);
      break;
  }
}

extern "C" void kernel_launch(void* const* d_in, const int* in_sizes, int n_in,
                              void* d_out, int out_size, void* d_ws,
                              size_t ws_size, hipStream_t stream) {
  const float* x = (const float*)d_in[0];
  const int* edge_index = (const int*)d_in[1];
  const int* esrc = edge_index;
  const int* edst = edge_index + NEDGES;

  const float* gw1[5] = {(const float*)d_in[3],  (const float*)d_in[7],
                         (const float*)d_in[11], (const float*)d_in[15],
                         (const float*)d_in[19]};
  const float* gb1[5] = {(const float*)d_in[4],  (const float*)d_in[8],
                         (const float*)d_in[12], (const float*)d_in[16],
                         (const float*)d_in[20]};
  const float* gw2[5] = {(const float*)d_in[5],  (const float*)d_in[9],
                         (const float*)d_in[13], (const float*)d_in[17],
                         (const float*)d_in[21]};
  const float* gb2[5] = {(const float*)d_in[6],  (const float*)d_in[10],
                         (const float*)d_in[14], (const float*)d_in[18],
                         (const float*)d_in[22]};
  const float* ng[4] = {(const float*)d_in[23], (const float*)d_in[25],
                        (const float*)d_in[27], (const float*)d_in[29]};
  const float* nb[4] = {(const float*)d_in[24], (const float*)d_in[26],
                        (const float*)d_in[28], (const float*)d_in[30]};

  // workspace layout
  unsigned short* AV = (unsigned short*)d_ws;            // N x 1024 bf16
  unsigned short* S = AV + (size_t)NNODES * 1024;        // N x 256 bf16 (BN input)
  unsigned short* Hbf = S + (size_t)NNODES * 256;        // N x 256 bf16 (L0 embed)
  unsigned short* Ybf = Hbf + (size_t)NNODES * 256;      // N x 512 bf16
  unsigned short* Wt1All = Ybf + (size_t)NNODES * 512;   // WT1_TOTAL bf16
  unsigned short* Wt2All = Wt1All + WT1_TOTAL;           // WT2_TOTAL bf16
  int* cnt = (int*)(Wt2All + WT2_TOTAL);                 // N
  int* rowptr = cnt + NNODES;                            // N+1
  int* head = rowptr + NNODES + 1;                       // N
  int* csr_src = head + NNODES;                          // E
  int* bsum = csr_src + NEDGES;                          // NB
  float* stats = (float*)(bsum + NB + 1);                // 4 layers x 1024

  const int Kpads[5] = {256, 64, 128, 256, 256};
  const int douts[5] = {64, 128, 256, 256, 512};
  const int wt1_off[5] = {0, 32768, 49152, 114688, 245760};
  const int wt2_off[5] = {0, 4096, 20480, 86016, 151552};

  WPtrs wp;
  for (int i = 0; i < 5; ++i) { wp.w1[i] = gw1[i]; wp.w2[i] = gw2[i]; }

  init_kernel<<<(NNODES + 4096 + 255) / 256, 256, 0, stream>>>(cnt, stats);
  count_embed_kernel<<<1250 + NB, 256, 0, stream>>>(edst, cnt, x, Hbf);
  scan_pass1<<<NB, 256, 0, stream>>>(cnt, bsum);
  scan_pass3<<<NB, 256, 0, stream>>>(cnt, bsum, rowptr, head);
  scatter_prep_kernel<<<1250 + (WT1_TOTAL + WT2_TOTAL + 255) / 256, 256, 0, stream>>>(
      esrc, edst, head, csr_src, wp, Wt1All, Wt2All);

  int lda = 256;  // L0: stride-256 bf16 embed output
  for (int L = 0; L < 5; ++L) {
    int Kp = Kpads[L], dout = douts[L];
    // ---- gemm1 (fused BN+ReLU for L>=1): AV = [H@W1a+b1 | H@W1b] ----
    {
      int ncolb = 2 * dout / 128;
      if (ncolb < 1) ncolb = 1;
      dim3 g1(GRID32(ncolb));
      if (L == 0) {
        hipLaunchKernelGGL((gemm128_kernel<0, 0, 32, 128>), g1, dim3(256), 0, stream,
                           (const void*)Hbf, lda, Kp, ncolb, Wt1All + wt1_off[L],
                           2 * dout, dout, gb1[L], (const int*)nullptr,
                           (const float*)nullptr, (const float*)nullptr,
                           (const float*)nullptr, (float*)nullptr, (void*)AV);
      } else {
        hipLaunchKernelGGL((gemm128_kernel<0, 1, 32, 128>), g1, dim3(256), 0, stream,
                           (const void*)S, Kp, Kp, ncolb, Wt1All + wt1_off[L],
                           2 * dout, dout, gb1[L], (const int*)nullptr,
                           stats + (L - 1) * 1024, ng[L - 1], nb[L - 1],
                           (float*)nullptr, (void*)AV);
      }
    }
    // ---- edge aggregation -> Ybf ----
    launch_edge_agg(dout, AV, rowptr, csr_src, Ybf, stream);
    // ---- gemm2 (+fused stats for L<4, bf16 S out) ----
    if (L == 0) {
      dim3 g2(GRID32(1));
      hipLaunchKernelGGL((gemm128_kernel<2, 0, 32, 64>), g2, dim3(256), 0, stream,
                         (const void*)Ybf, dout, dout, 1, Wt2All + wt2_off[L],
                         dout, dout, gb2[L], cnt, (const float*)nullptr,
                         (const float*)nullptr, (const float*)nullptr,
                         stats + L * 1024, (void*)S);
    } else if (L < 4) {
      int ncolb = dout / 128;
      dim3 g2(GRID32(ncolb));
      hipLaunchKernelGGL((gemm128_kernel<2, 0, 32, 128>), g2, dim3(256), 0, stream,
                         (const void*)Ybf, dout, dout, ncolb, Wt2All + wt2_off[L],
                         dout, dout, gb2[L], cnt, (const float*)nullptr,
                         (const float*)nullptr, (const float*)nullptr,
                         stats + L * 1024, (void*)S);
    } else {
      int ncolb = dout / 128;
      dim3 g2(GRID32(ncolb));
      hipLaunchKernelGGL((gemm128_kernel<1, 0, 32, 128>), g2, dim3(256), 0, stream,
                         (const void*)Ybf, dout, dout, ncolb, Wt2All + wt2_off[L],
                         dout, dout, gb2[L], cnt, (const float*)nullptr,
                         (const float*)nullptr, (const float*)nullptr,
                         (float*)nullptr, (void*)d_out);
    }
  }
}

// Round 19
// 369.384 us; speedup vs baseline: 1.1528x; 1.1528x over previous
//
#include <hip/hip_runtime.h>
#include <math.h>

#define NNODES 20000
#define NEDGES 320000
#define NB 79      // ceil(NNODES/256)
#define MB64 313   // ceil(NNODES/64)
#define M64Q 39    // MB64/8
#define M64R 1     // MB64%8

typedef __bf16 bf16x8 __attribute__((ext_vector_type(8)));
typedef float f32x4 __attribute__((ext_vector_type(4)));
typedef unsigned short u16x8 __attribute__((ext_vector_type(8)));

__device__ inline unsigned short f2bf(float x) {
  union { float f; unsigned int u; } q;
  q.f = x;
  unsigned int u = q.u;
  unsigned int r = (u + 0x7fffu + ((u >> 16) & 1u)) >> 16;
  return (unsigned short)r;
}

__device__ inline float bf2f(unsigned short u) {
  union { unsigned int u; float f; } q;
  q.u = ((unsigned int)u) << 16;
  return q.f;
}

// async 16B global->LDS (wave-uniform LDS base + lane*16; per-lane global src)
__device__ inline void load_lds16(const unsigned short* g, unsigned short* l) {
  __builtin_amdgcn_global_load_lds(
      (const __attribute__((address_space(1))) unsigned int*)g,
      (__attribute__((address_space(3))) unsigned int*)l, 16, 0, 0);
}

// ---------------- init: zero cnt + stats ----------------
__global__ __launch_bounds__(256) void init_kernel(int* __restrict__ cnt,
                                                   float* __restrict__ stats) {
  int idx = blockIdx.x * 256 + threadIdx.x;
  if (idx < NNODES) cnt[idx] = 0;
  int j = idx - NNODES;
  if (j >= 0 && j < 4096) stats[j] = 0.f;
}

// ---------------- fused: count (blocks 0..1249) + embed (rest) ----------------
__global__ __launch_bounds__(256) void count_embed_kernel(
    const int* __restrict__ edst, int* __restrict__ cnt,
    const float* __restrict__ x, unsigned short* __restrict__ h) {
  int bid = blockIdx.x;
  if (bid < 1250) {
    int e = bid * 256 + threadIdx.x;
    atomicAdd(&cnt[edst[e]], 1);
    return;
  }
  int n = (bid - 1250) * 256 + threadIdx.x;
  if (n >= NNODES) return;
  const float* xr = x + (size_t)n * 20;
  unsigned short* hr = h + (size_t)n * 256;
#pragma unroll
  for (int g = 0; g < 3; ++g) {
    float v0 = xr[g * 3 + 0], v1 = xr[g * 3 + 1], v2 = xr[g * 3 + 2];
    unsigned short* o = hr + g * 63;
    o[0] = f2bf(v0); o[1] = f2bf(v1); o[2] = f2bf(v2);
    float f = 1.0f;
    for (int fr = 0; fr < 10; ++fr) {
      float s0, c0, s1, c1, s2, c2;
      sincosf(v0 * f, &s0, &c0);
      sincosf(v1 * f, &s1, &c1);
      sincosf(v2 * f, &s2, &c2);
      int base = 3 + fr * 6;
      o[base + 0] = f2bf(s0); o[base + 1] = f2bf(s1); o[base + 2] = f2bf(s2);
      o[base + 3] = f2bf(c0); o[base + 4] = f2bf(c1); o[base + 5] = f2bf(c2);
      f *= 2.0f;
    }
  }
  for (int j = 0; j < 11; ++j) hr[189 + j] = f2bf(xr[9 + j]);
  for (int j = 200; j < 256; ++j) hr[j] = 0;
}

// ---------------- scan pass1: per-block sums ----------------
__global__ __launch_bounds__(256) void scan_pass1(const int* __restrict__ cnt,
                                                  int* __restrict__ bsum) {
  __shared__ int red[256];
  int i = blockIdx.x * 256 + threadIdx.x;
  int v = (i < NNODES) ? cnt[i] : 0;
  red[threadIdx.x] = v;
  __syncthreads();
#pragma unroll
  for (int off = 128; off > 0; off >>= 1) {
    if (threadIdx.x < off) red[threadIdx.x] += red[threadIdx.x + off];
    __syncthreads();
  }
  if (threadIdx.x == 0) bsum[blockIdx.x] = red[0];
}

// ---------------- scan pass3: redundant bsum-scan + local scan -> rowptr/head ----
__global__ __launch_bounds__(256) void scan_pass3(const int* __restrict__ cnt,
                                                  const int* __restrict__ bsum,
                                                  int* __restrict__ rowptr,
                                                  int* __restrict__ head) {
  __shared__ int pref[128];
  __shared__ int buf[256];
  int t = threadIdx.x;
  if (t < 128) {
    int v = (t < NB) ? bsum[t] : 0;
    pref[t] = v;
  }
  __syncthreads();
#pragma unroll
  for (int off = 1; off < 128; off <<= 1) {
    int u = (t < 128 && t >= off) ? pref[t - off] : 0;
    __syncthreads();
    if (t < 128) pref[t] += u;
    __syncthreads();
  }
  int boff = (blockIdx.x == 0) ? 0 : pref[blockIdx.x - 1];
  int i = blockIdx.x * 256 + t;
  int v = (i < NNODES) ? cnt[i] : 0;
  buf[t] = v;
  __syncthreads();
#pragma unroll
  for (int off = 1; off < 256; off <<= 1) {
    int u = (t >= off) ? buf[t - off] : 0;
    __syncthreads();
    buf[t] += u;
    __syncthreads();
  }
  if (i < NNODES) {
    int excl = boff + buf[t] - v;
    rowptr[i] = excl;
    head[i] = excl;
  }
  if (i == 0) rowptr[NNODES] = NEDGES;
}

// ---------------- fused: scatter (blocks 0..1249) + weight prep (rest) ----------
struct WPtrs {
  const float* w1[5];
  const float* w2[5];
};

#define WT1_TOTAL 507904
#define WT2_TOTAL 413696

__global__ __launch_bounds__(256) void scatter_prep_kernel(
    const int* __restrict__ esrc, const int* __restrict__ edst,
    int* __restrict__ head, int* __restrict__ csr_src, WPtrs p,
    unsigned short* __restrict__ Wt1All, unsigned short* __restrict__ Wt2All) {
  int bid = blockIdx.x;
  if (bid < 1250) {
    int e = bid * 256 + threadIdx.x;
    int pos = atomicAdd(&head[edst[e]], 1);
    csr_src[pos] = esrc[e];
    return;
  }
  int idx = (bid - 1250) * 256 + threadIdx.x;
  if (idx < WT1_TOTAL) {
    int L, off, din, dout, Kpad;
    if (idx < 32768)       { L = 0; off = 0;      din = 200; dout = 64;  Kpad = 256; }
    else if (idx < 49152)  { L = 1; off = 32768;  din = 64;  dout = 128; Kpad = 64;  }
    else if (idx < 114688) { L = 2; off = 49152;  din = 128; dout = 256; Kpad = 128; }
    else if (idx < 245760) { L = 3; off = 114688; din = 256; dout = 256; Kpad = 256; }
    else                   { L = 4; off = 245760; din = 256; dout = 512; Kpad = 256; }
    int local = idx - off;
    int c = local / Kpad, k = local % Kpad;
    float v = 0.f;
    if (k < din)
      v = (c < dout) ? p.w1[L][(size_t)k * dout + c]
                     : p.w1[L][(size_t)(din + k) * dout + (c - dout)];
    Wt1All[idx] = f2bf(v);
    return;
  }
  int jdx = idx - WT1_TOTAL;
  if (jdx >= WT2_TOTAL) return;
  int L, off, d;
  if (jdx < 4096)        { L = 0; off = 0;      d = 64;  }
  else if (jdx < 20480)  { L = 1; off = 4096;   d = 128; }
  else if (jdx < 86016)  { L = 2; off = 20480;  d = 256; }
  else if (jdx < 151552) { L = 3; off = 86016;  d = 256; }
  else                   { L = 4; off = 151552; d = 512; }
  int local = jdx - off;
  int n = local / d, k = local % d;
  Wt2All[jdx] = f2bf(p.w2[L][(size_t)k * d + n]);
}

// ======== 64xBN MFMA GEMM, BK=64, XCD-aware 1D grid, high-occupancy ========
// BN in {64,128}. LDS: sA[64][64] + sB[BN][64], chunk-XOR swizzle.
// C-write via LDS transpose -> 16B-coalesced stores.
// s_setprio(1) around the MFMA cluster (T5: independent blocks, mixed phases).
// EPIA 0: A bf16 via gload_lds; EPIA 1: A bf16 S with fused BN+ReLU.
// EPI 0: Cout bf16 = acc + (col<dhalf ? bias : 0)
// EPI 1: Cout f32  = cnt[row]>0 ? acc + bias : 0        (final layer; BN=128)
// EPI 2: Cout bf16 = masked+bias, + atomic column stats (sum, sumsq)
template <int EPI, int EPIA, int BN>
__global__ __launch_bounds__(256) void gemm128_kernel(
    const void* __restrict__ Aptr, int lda, int K, int ncolb,
    const unsigned short* __restrict__ Bt, int Ncol, int dhalf,
    const float* __restrict__ bias, const int* __restrict__ cnt,
    const float* __restrict__ pstats, const float* __restrict__ pg,
    const float* __restrict__ pb, float* __restrict__ stats,
    void* __restrict__ Cout) {
  constexpr int NFC = BN / 64;
  constexpr int BGRP = BN / 32;
  constexpr int CPW = BN / 32;
  int bid = blockIdx.x;
  int xcd = bid & 7;
  int j = bid >> 3;
  int cntx = M64Q + (xcd < M64R ? 1 : 0);
  int row_local = j / ncolb;
  if (row_local >= cntx) return;
  int colb = j - row_local * ncolb;
  int row0 = xcd * M64Q + min(xcd, M64R);
  int bR = (row0 + row_local) * 64;
  int bC = colb * BN;

  __shared__ unsigned short sBuf[64 * 64 + BN * 64];
  __shared__ float sScale[EPIA == 1 ? 256 : 1], sShift[EPIA == 1 ? 256 : 1];
  unsigned short* sA = sBuf;
  unsigned short* sB = sBuf + 64 * 64;
  int tid = threadIdx.x;
  int wid = tid >> 6, lane = tid & 63;
  int lr = lane & 15, lg = lane >> 4;
  int sub = lane >> 3;
  int ckl = (lane & 7) ^ sub;

  if (EPIA == 1) {
    for (int c = tid; c < K; c += 256) {
      float mu = pstats[c] * (1.0f / NNODES);
      float var = pstats[K + c] * (1.0f / NNODES) - mu * mu;
      float sc = pg[c] * rsqrtf(var + 1e-5f);
      sScale[c] = sc;
      sShift[c] = pb[c] - mu * sc;
    }
    __syncthreads();
  }

  f32x4 acc[4][NFC];
#pragma unroll
  for (int fr = 0; fr < 4; ++fr)
#pragma unroll
    for (int fc = 0; fc < NFC; ++fc) acc[fr][fc] = f32x4{0.f, 0.f, 0.f, 0.f};

  for (int k0 = 0; k0 < K; k0 += 64) {
    // ---- stage A tile [64][64] ----
    if (EPIA == 0) {
      const unsigned short* Ab = (const unsigned short*)Aptr;
#pragma unroll
      for (int q = 0; q < 2; ++q) {
        int t = wid * 2 + q;
        int gr = bR + t * 8 + sub;
        if (gr > NNODES - 1) gr = NNODES - 1;  // clamp; rows >= N never written out
        load_lds16(Ab + (size_t)gr * lda + k0 + ckl * 8, sA + t * 512);
      }
    } else {
      const unsigned short* Ab = (const unsigned short*)Aptr;
#pragma unroll
      for (int i = 0; i < 2; ++i) {
        int idx = tid + i * 256;
        int row = idx >> 3, c = idx & 7;
        int gr = bR + row;
        u16x8 o;
        if (gr < NNODES) {
          u16x8 s8 = *(const u16x8*)(Ab + (size_t)gr * lda + k0 + c * 8);
#pragma unroll
          for (int jj = 0; jj < 8; ++jj) {
            int k = k0 + c * 8 + jj;
            o[jj] = f2bf(fmaxf(bf2f(s8[jj]) * sScale[k] + sShift[k], 0.f));
          }
        } else {
#pragma unroll
          for (int jj = 0; jj < 8; ++jj) o[jj] = 0;
        }
        int ck = c ^ (row & 7);
        *(u16x8*)(sA + row * 64 + ck * 8) = o;
      }
    }
    // ---- stage B tile [BN][64] ----
#pragma unroll
    for (int q = 0; q < BGRP; ++q) {
      int t = wid * BGRP + q;
      int gn = bC + t * 8 + sub;
      load_lds16(Bt + (size_t)gn * K + k0 + ckl * 8, sB + t * 512);
    }
    __syncthreads();
    __builtin_amdgcn_s_setprio(1);
#pragma unroll
    for (int ks = 0; ks < 2; ++ks) {
      bf16x8 aF[4], bF[NFC];
      int cb = ks * 4 + lg;
      int ck = cb ^ (lr & 7);
#pragma unroll
      for (int fr = 0; fr < 4; ++fr)
        aF[fr] = *(const bf16x8*)(sA + (fr * 16 + lr) * 64 + ck * 8);
#pragma unroll
      for (int fc = 0; fc < NFC; ++fc)
        bF[fc] = *(const bf16x8*)(sB + (wid * NFC * 16 + fc * 16 + lr) * 64 + ck * 8);
#pragma unroll
      for (int fr = 0; fr < 4; ++fr)
#pragma unroll
        for (int fc = 0; fc < NFC; ++fc)
          acc[fr][fc] = __builtin_amdgcn_mfma_f32_16x16x32_bf16(
              aF[fr], bF[fc], acc[fr][fc], 0, 0, 0);
    }
    __builtin_amdgcn_s_setprio(0);
    __syncthreads();
  }

  // ---- epilogue ----
  if constexpr (EPI == 0 || EPI == 2) {
    float csum[NFC], csum2[NFC];
#pragma unroll
    for (int fc = 0; fc < NFC; ++fc) { csum[fc] = 0.f; csum2[fc] = 0.f; }
#pragma unroll
    for (int fr = 0; fr < 4; ++fr) {
#pragma unroll
      for (int jj = 0; jj < 4; ++jj) {
        int row = fr * 16 + lg * 4 + jj;
        int gr = bR + row;
        int ct = 1;
        if (EPI == 2) ct = (gr < NNODES) ? cnt[gr] : 0;
#pragma unroll
        for (int fc = 0; fc < NFC; ++fc) {
          int col = wid * NFC * 16 + fc * 16 + lr;
          int gc = bC + col;
          float v = acc[fr][fc][jj];
          if (EPI == 0) {
            if (gc < dhalf) v += bias[gc];
          } else {
            v = (ct > 0) ? (v + bias[gc]) : 0.f;
            if (gr < NNODES) {
              csum[fc] += v;
              csum2[fc] += v * v;
            }
          }
          sBuf[row * BN + col] = f2bf(v);
        }
      }
    }
    if (EPI == 2) {
#pragma unroll
      for (int fc = 0; fc < NFC; ++fc) {
        float s = csum[fc], s2 = csum2[fc];
        s += __shfl_xor(s, 16, 64);
        s += __shfl_xor(s, 32, 64);
        s2 += __shfl_xor(s2, 16, 64);
        s2 += __shfl_xor(s2, 32, 64);
        if (lg == 0) {
          int gc = bC + wid * NFC * 16 + fc * 16 + lr;
          atomicAdd(&stats[gc], s);
          atomicAdd(&stats[Ncol + gc], s2);
        }
      }
    }
    __syncthreads();
#pragma unroll
    for (int i = 0; i < CPW; ++i) {
      int idx = tid + i * 256;
      int row = idx / (BN / 8), c8 = (idx % (BN / 8)) * 8;
      int gr = bR + row;
      if (gr < NNODES)
        *(u16x8*)((unsigned short*)Cout + (size_t)gr * Ncol + bC + c8) =
            *(const u16x8*)(sBuf + row * BN + c8);
    }
  } else {
    // EPI 1 (BN=128 only): f32 output in two col-half passes via 64x64 f32 tile
    float* sF = (float*)sBuf;
#pragma unroll
    for (int h = 0; h < 2; ++h) {
      if ((wid >> 1) == h) {
#pragma unroll
        for (int fr = 0; fr < 4; ++fr) {
#pragma unroll
          for (int jj = 0; jj < 4; ++jj) {
            int row = fr * 16 + lg * 4 + jj;
            int gr = bR + row;
            int ct = (gr < NNODES) ? cnt[gr] : 0;
#pragma unroll
            for (int fc = 0; fc < NFC; ++fc) {
              int lcol = (wid & 1) * 32 + fc * 16 + lr;
              int gc = bC + h * 64 + lcol;
              float v = acc[fr][fc][jj];
              v = (ct > 0) ? (v + bias[gc]) : 0.f;
              sF[row * 64 + lcol] = v;
            }
          }
        }
      }
      __syncthreads();
#pragma unroll
      for (int i = 0; i < 4; ++i) {
        int idx = tid + i * 256;
        int row = idx >> 4, c4 = (idx & 15) * 4;
        int gr = bR + row;
        if (gr < NNODES)
          *(float4*)((float*)Cout + (size_t)gr * Ncol + bC + h * 64 + c4) =
              *(const float4*)(sF + row * 64 + c4);
      }
      __syncthreads();
    }
  }
}

// ------- edge aggregation (gather, bf16, XCD column-sliced, 4-deep unroll) -------
template <int D, int SLICES>
__global__ __launch_bounds__(256) void edge_agg_kernel(
    const unsigned short* __restrict__ AV, const int* __restrict__ rowptr,
    const int* __restrict__ csr_src, unsigned short* __restrict__ Y) {
  int slice = blockIdx.x % SLICES;
  int ngrp = blockIdx.x / SLICES;
  int tid = threadIdx.x;
  int ln = tid & 7;
  int sn = tid >> 3;
  int node = ngrp * 32 + sn;
  if (node >= NNODES) return;
  int c = slice * 64 + ln * 8;
  const unsigned short* Arow = AV + (size_t)node * 2 * D;
  u16x8 a8 = *(const u16x8*)(Arow + c);
  u16x8 v8 = *(const u16x8*)(Arow + D + c);
  float ad[8], acc[8];
#pragma unroll
  for (int i = 0; i < 8; ++i) {
    ad[i] = bf2f(a8[i]) - bf2f(v8[i]);
    acc[i] = 0.f;
  }
  int e0 = rowptr[node], e1 = rowptr[node + 1];
  int e = e0;
  for (; e + 3 < e1; e += 4) {
    int s0 = csr_src[e], s1 = csr_src[e + 1];
    int s2 = csr_src[e + 2], s3 = csr_src[e + 3];
    u16x8 w0 = *(const u16x8*)(AV + (size_t)s0 * 2 * D + D + c);
    u16x8 w1 = *(const u16x8*)(AV + (size_t)s1 * 2 * D + D + c);
    u16x8 w2 = *(const u16x8*)(AV + (size_t)s2 * 2 * D + D + c);
    u16x8 w3 = *(const u16x8*)(AV + (size_t)s3 * 2 * D + D + c);
#pragma unroll
    for (int i = 0; i < 8; ++i) {
      acc[i] += fmaxf(ad[i] + bf2f(w0[i]), 0.f) + fmaxf(ad[i] + bf2f(w1[i]), 0.f) +
                fmaxf(ad[i] + bf2f(w2[i]), 0.f) + fmaxf(ad[i] + bf2f(w3[i]), 0.f);
    }
  }
  for (; e < e1; ++e) {
    int s0 = csr_src[e];
    u16x8 w0 = *(const u16x8*)(AV + (size_t)s0 * 2 * D + D + c);
#pragma unroll
    for (int i = 0; i < 8; ++i) acc[i] += fmaxf(ad[i] + bf2f(w0[i]), 0.f);
  }
  float inv = (e1 > e0) ? 1.f / (float)(e1 - e0) : 0.f;
  u16x8 o;
#pragma unroll
  for (int i = 0; i < 8; ++i) o[i] = f2bf(acc[i] * inv);
  *(u16x8*)(Y + (size_t)node * D + c) = o;
}

static void launch_edge_agg(int dout, const unsigned short* AV, const int* rowptr,
                            const int* csr_src, unsigned short* Y,
                            hipStream_t st) {
  const int NG = (NNODES + 31) / 32;
  switch (dout) {
    case 64:
      hipLaunchKernelGGL((edge_agg_kernel<64, 1>), dim3(NG * 1), dim3(256), 0, st,
                         AV, rowptr, csr_src, Y);
      break;
    case 128:
      hipLaunchKernelGGL((edge_agg_kernel<128, 2>), dim3(NG * 2), dim3(256), 0, st,
                         AV, rowptr, csr_src, Y);
      break;
    case 256:
      hipLaunchKernelGGL((edge_agg_kernel<256, 4>), dim3(NG * 4), dim3(256), 0, st,
                         AV, rowptr, csr_src, Y);
      break;
    case 512:
      hipLaunchKernelGGL((edge_agg_kernel<512, 8>), dim3(NG * 8), dim3(256), 0, st,
                         AV, rowptr, csr_src, Y);
      break;
  }
}

extern "C" void kernel_launch(void* const* d_in, const int* in_sizes, int n_in,
                              void* d_out, int out_size, void* d_ws,
                              size_t ws_size, hipStream_t stream) {
  const float* x = (const float*)d_in[0];
  const int* edge_index = (const int*)d_in[1];
  const int* esrc = edge_index;
  const int* edst = edge_index + NEDGES;

  const float* gw1[5] = {(const float*)d_in[3],  (const float*)d_in[7],
                         (const float*)d_in[11], (const float*)d_in[15],
                         (const float*)d_in[19]};
  const float* gb1[5] = {(const float*)d_in[4],  (const float*)d_in[8],
                         (const float*)d_in[12], (const float*)d_in[16],
                         (const float*)d_in[20]};
  const float* gw2[5] = {(const float*)d_in[5],  (const float*)d_in[9],
                         (const float*)d_in[13], (const float*)d_in[17],
                         (const float*)d_in[21]};
  const float* gb2[5] = {(const float*)d_in[6],  (const float*)d_in[10],
                         (const float*)d_in[14], (const float*)d_in[18],
                         (const float*)d_in[22]};
  const float* ng[4] = {(const float*)d_in[23], (const float*)d_in[25],
                        (const float*)d_in[27], (const float*)d_in[29]};
  const float* nb[4] = {(const float*)d_in[24], (const float*)d_in[26],
                        (const float*)d_in[28], (const float*)d_in[30]};

  // workspace layout
  unsigned short* AV = (unsigned short*)d_ws;            // N x 1024 bf16
  unsigned short* S = AV + (size_t)NNODES * 1024;        // N x 256 bf16 (BN input)
  unsigned short* Hbf = S + (size_t)NNODES * 256;        // N x 256 bf16 (L0 embed)
  unsigned short* Ybf = Hbf + (size_t)NNODES * 256;      // N x 512 bf16
  unsigned short* Wt1All = Ybf + (size_t)NNODES * 512;   // WT1_TOTAL bf16
  unsigned short* Wt2All = Wt1All + WT1_TOTAL;           // WT2_TOTAL bf16
  int* cnt = (int*)(Wt2All + WT2_TOTAL);                 // N
  int* rowptr = cnt + NNODES;                            // N+1
  int* head = rowptr + NNODES + 1;                       // N
  int* csr_src = head + NNODES;                          // E
  int* bsum = csr_src + NEDGES;                          // NB
  float* stats = (float*)(bsum + NB + 1);                // 4 layers x 1024

  const int Kpads[5] = {256, 64, 128, 256, 256};
  const int douts[5] = {64, 128, 256, 256, 512};
  const int wt1_off[5] = {0, 32768, 49152, 114688, 245760};
  const int wt2_off[5] = {0, 4096, 20480, 86016, 151552};

  WPtrs wp;
  for (int i = 0; i < 5; ++i) { wp.w1[i] = gw1[i]; wp.w2[i] = gw2[i]; }

  init_kernel<<<(NNODES + 4096 + 255) / 256, 256, 0, stream>>>(cnt, stats);
  count_embed_kernel<<<1250 + NB, 256, 0, stream>>>(edst, cnt, x, Hbf);
  scan_pass1<<<NB, 256, 0, stream>>>(cnt, bsum);
  scan_pass3<<<NB, 256, 0, stream>>>(cnt, bsum, rowptr, head);
  scatter_prep_kernel<<<1250 + (WT1_TOTAL + WT2_TOTAL + 255) / 256, 256, 0, stream>>>(
      esrc, edst, head, csr_src, wp, Wt1All, Wt2All);

  int lda = 256;  // L0: stride-256 bf16 embed output
  for (int L = 0; L < 5; ++L) {
    int Kp = Kpads[L], dout = douts[L];
    // ---- gemm1 (fused BN+ReLU for L>=1): AV = [H@W1a+b1 | H@W1b] ----
    {
      int ncolb = 2 * dout / 128;
      if (ncolb < 1) ncolb = 1;
      dim3 g1(8 * (M64Q + 1) * ncolb);
      if (L == 0) {
        hipLaunchKernelGGL((gemm128_kernel<0, 0, 128>), g1, dim3(256), 0, stream,
                           (const void*)Hbf, lda, Kp, ncolb, Wt1All + wt1_off[L],
                           2 * dout, dout, gb1[L], (const int*)nullptr,
                           (const float*)nullptr, (const float*)nullptr,
                           (const float*)nullptr, (float*)nullptr, (void*)AV);
      } else {
        hipLaunchKernelGGL((gemm128_kernel<0, 1, 128>), g1, dim3(256), 0, stream,
                           (const void*)S, Kp, Kp, ncolb, Wt1All + wt1_off[L],
                           2 * dout, dout, gb1[L], (const int*)nullptr,
                           stats + (L - 1) * 1024, ng[L - 1], nb[L - 1],
                           (float*)nullptr, (void*)AV);
      }
    }
    // ---- edge aggregation -> Ybf ----
    launch_edge_agg(dout, AV, rowptr, csr_src, Ybf, stream);
    // ---- gemm2 (+fused stats for L<4, bf16 S out) ----
    if (L == 0) {
      dim3 g2(8 * (M64Q + 1));
      hipLaunchKernelGGL((gemm128_kernel<2, 0, 64>), g2, dim3(256), 0, stream,
                         (const void*)Ybf, dout, dout, 1, Wt2All + wt2_off[L],
                         dout, dout, gb2[L], cnt, (const float*)nullptr,
                         (const float*)nullptr, (const float*)nullptr,
                         stats + L * 1024, (void*)S);
    } else if (L < 4) {
      int ncolb = dout / 128;
      dim3 g2(8 * (M64Q + 1) * ncolb);
      hipLaunchKernelGGL((gemm128_kernel<2, 0, 128>), g2, dim3(256), 0, stream,
                         (const void*)Ybf, dout, dout, ncolb, Wt2All + wt2_off[L],
                         dout, dout, gb2[L], cnt, (const float*)nullptr,
                         (const float*)nullptr, (const float*)nullptr,
                         stats + L * 1024, (void*)S);
    } else {
      int ncolb = dout / 128;
      dim3 g2(8 * (M64Q + 1) * ncolb);
      hipLaunchKernelGGL((gemm128_kernel<1, 0, 128>), g2, dim3(256), 0, stream,
                         (const void*)Ybf, dout, dout, ncolb, Wt2All + wt2_off[L],
                         dout, dout, gb2[L], cnt, (const float*)nullptr,
                         (const float*)nullptr, (const float*)nullptr,
                         (float*)nullptr, (void*)d_out);
    }
  }
}